// Round 1
// 384.899 us; speedup vs baseline: 1.1479x; 1.1479x over previous
//
#include <hip/hip_runtime.h>
#include <stdint.h>
#include <stddef.h>

#define IN_F 4096
#define OUT_F 4096

typedef int i32x4 __attribute__((ext_vector_type(4)));
typedef float f32x4 __attribute__((ext_vector_type(4)));

// ---------- helpers ----------

__device__ static inline void async16(const void* g, void* l) {
    __builtin_amdgcn_global_load_lds(
        (const __attribute__((address_space(1))) unsigned int*)g,
        (__attribute__((address_space(3))) unsigned int*)l,
        16, 0, 0);
}

__device__ static inline double wred_d(double v) {
#pragma unroll
    for (int o = 32; o > 0; o >>= 1) v += __shfl_down(v, o, 64);
    return v;
}

__device__ static inline int wred_i(int v) {
#pragma unroll
    for (int o = 32; o > 0; o >>= 1) v += __shfl_down(v, o, 64);
    return v;
}

__device__ static inline float wred_max(float v) {
#pragma unroll
    for (int o = 32; o > 0; o >>= 1) v = fmaxf(v, __shfl_down(v, o, 64));
    return v;
}

// ---------- K1: fused per-row stats + ternarize -> T i8 {-1,0,1} ----------

__global__ __launch_bounds__(256) void rowstats_tern_kernel(
    const float* __restrict__ w,
    float* __restrict__ alpha_o,
    int8_t* __restrict__ T) {
    __shared__ float rowbuf[OUT_F];          // 16 KB
    __shared__ double sh_s[4], sh_m[4];
    __shared__ int sh_c[4];
    const int row = blockIdx.x;
    const int t = threadIdx.x;
    const int lane = t & 63, wv = t >> 6;
    const float4* wr = (const float4*)(w + (size_t)row * OUT_F);

    double s = 0.0;
#pragma unroll
    for (int it = 0; it < 4; ++it) {
        float4 v = wr[t + it * 256];
        ((float4*)rowbuf)[t + it * 256] = v;
        s += (double)fabsf(v.x) + (double)fabsf(v.y) +
             (double)fabsf(v.z) + (double)fabsf(v.w);
    }
    double sw = wred_d(s);
    if (lane == 0) sh_s[wv] = sw;
    __syncthreads();
    const double delta = (sh_s[0] + sh_s[1] + sh_s[2] + sh_s[3]) *
                         (0.7 / (double)OUT_F);

    int8_t* trow = T + (size_t)row * OUT_F;
    double ms = 0.0;
    int cnt = 0;
#pragma unroll
    for (int k = 0; k < 16; ++k) {
        float v = rowbuf[k * 256 + t];
        double a = (double)fabsf(v);
        if (a > delta) { ms += a; ++cnt; }
        int8_t q = 0;
        if ((double)v > delta)       q = 1;
        else if ((double)v < -delta) q = -1;
        trow[k * 256 + t] = q;
    }
    double msw = wred_d(ms);
    int cw = wred_i(cnt);
    if (lane == 0) { sh_m[wv] = msw; sh_c[wv] = cw; }
    __syncthreads();
    if (t == 0) {
        double mtot = sh_m[0] + sh_m[1] + sh_m[2] + sh_m[3];
        int ctot = sh_c[0] + sh_c[1] + sh_c[2] + sh_c[3];
        alpha_o[row] = (float)(mtot / (double)ctot);
    }
}

// ---------- K2: i8 transpose T[IN][OUT] -> Tt[OUT][IN] ----------

__global__ __launch_bounds__(256) void transpose_i8_kernel(
    const int8_t* __restrict__ T,
    int8_t* __restrict__ Tt) {
    __shared__ int8_t lds[64][72];
    const int t = threadIdx.x;
    const int i0 = blockIdx.y * 64;  // IN
    const int j0 = blockIdx.x * 64;  // OUT

#pragma unroll
    for (int it = 0; it < 4; ++it) {
        int idx = it * 256 + t;
        int r = idx >> 4;
        int c4 = idx & 15;
        uchar4 v = *(const uchar4*)(T + (size_t)(i0 + r) * OUT_F + j0 + c4 * 4);
        lds[c4 * 4 + 0][r] = (int8_t)v.x;
        lds[c4 * 4 + 1][r] = (int8_t)v.y;
        lds[c4 * 4 + 2][r] = (int8_t)v.z;
        lds[c4 * 4 + 3][r] = (int8_t)v.w;
    }
    __syncthreads();
#pragma unroll
    for (int it = 0; it < 2; ++it) {
        int idx = it * 256 + t;
        int rr = idx >> 3;
        int cc = idx & 7;
        unsigned long long v = *(const unsigned long long*)&lds[rr][cc * 8];
        *(unsigned long long*)(Tt + (size_t)(j0 + rr) * IN_F + i0 + cc * 8) = v;
    }
}

// ---------- K3: per-batch-row quantize ----------

__global__ __launch_bounds__(256) void xquant_kernel(
    const float* __restrict__ x,
    const float* __restrict__ alpha,
    int8_t* __restrict__ xq,
    float* __restrict__ scale_o) {
    __shared__ float rowbuf[IN_F];
    __shared__ float sh_mx[4];
    const int row = blockIdx.x;
    const int t = threadIdx.x;
    const int lane = t & 63, wv = t >> 6;
    const float4* xr = (const float4*)(x + (size_t)row * IN_F);
    const float4* ar = (const float4*)alpha;

    float mx = 0.0f;
#pragma unroll
    for (int it = 0; it < 4; ++it) {
        float4 v = xr[t + it * 256];
        float4 a = ar[t + it * 256];
        v.x *= a.x; v.y *= a.y; v.z *= a.z; v.w *= a.w;
        ((float4*)rowbuf)[t + it * 256] = v;
        mx = fmaxf(mx, fmaxf(fmaxf(fabsf(v.x), fabsf(v.y)),
                             fmaxf(fabsf(v.z), fabsf(v.w))));
    }
    float mw = wred_max(mx);
    if (lane == 0) sh_mx[wv] = mw;
    __syncthreads();
    const float rmax = fmaxf(fmaxf(sh_mx[0], sh_mx[1]), fmaxf(sh_mx[2], sh_mx[3]));
    const float inv = (rmax > 0.0f) ? (127.0f / rmax) : 0.0f;

    int8_t* qrow = xq + (size_t)row * IN_F;
#pragma unroll
    for (int k = 0; k < 16; ++k) {
        float v = rowbuf[k * 256 + t];
        qrow[k * 256 + t] = (int8_t)__float2int_rn(v * inv);
    }
    if (t == 0) scale_o[row] = (rmax > 0.0f) ? (rmax / 127.0f) : 1.0f;
}

// ---------- K4: i8 MFMA GEMM, 256x256 8-phase schedule (HK-template port) ----
// BM=BN=256, BK=128 bytes, 512 thr (8 waves 2Mx4N), 128 KiB dbuf LDS.
// T2: chunk-XOR swizzle slot = q ^ (row&7)  (global-source pre-swizzle +
//     swizzled ds_read; linear global_load_lds dest).
// T3/T4: 1 half-tile (2x gload_lds) staged per phase; counted vmcnt(2) at
//     phase-3/7 boundaries only (never 0 mid-loop).
// T5: setprio(1) around each 16-MFMA cluster.  T1: bijective XCD swizzle.

#define GBARRIER() asm volatile("s_barrier" ::: "memory")

// stage one half-tile (128 rows x 128 B) of operand G (row stride IN_F bytes)
#define STAGE(G, GR0, TILE, LBASE, HALF)                                        \
    do {                                                                        \
        _Pragma("unroll")                                                       \
        for (int rr_ = 0; rr_ < 2; ++rr_) {                                     \
            const int L_ = (HALF) * 1024 + rr_ * 512 + t;                       \
            const int row_ = L_ >> 3;                                           \
            const int gch_ = (L_ & 7) ^ (row_ & 7);                             \
            async16((G) + (size_t)((GR0) + row_) * IN_F + (TILE) * 128 +        \
                        (gch_ << 4),                                            \
                    (LBASE) + (L_ << 4));                                       \
        }                                                                       \
    } while (0)

#define READ_A(BUF, MI0)                                                        \
    _Pragma("unroll")                                                           \
    for (int mi_ = 0; mi_ < 4; ++mi_) {                                         \
        a[2 * mi_]     = *(const i32x4*)((BUF) + offA_k0 + ((MI0) + mi_) * 2048); \
        a[2 * mi_ + 1] = *(const i32x4*)((BUF) + offA_k1 + ((MI0) + mi_) * 2048); \
    }

#define READ_B(BUF, NI0, DST)                                                   \
    _Pragma("unroll")                                                           \
    for (int ni_ = 0; ni_ < 2; ++ni_) {                                         \
        DST[2 * ni_]     = *(const i32x4*)((BUF) + offB_k0 + ((NI0) + ni_) * 2048); \
        DST[2 * ni_ + 1] = *(const i32x4*)((BUF) + offB_k1 + ((NI0) + ni_) * 2048); \
    }

#define MFMA_Q(MI0, NI0, BSRC)                                                  \
    do {                                                                        \
        __builtin_amdgcn_s_setprio(1);                                          \
        _Pragma("unroll")                                                       \
        for (int mi_ = 0; mi_ < 4; ++mi_) {                                     \
            _Pragma("unroll")                                                   \
            for (int ni_ = 0; ni_ < 2; ++ni_) {                                 \
                acc[(MI0) + mi_][(NI0) + ni_] =                                 \
                    __builtin_amdgcn_mfma_i32_16x16x64_i8(                      \
                        a[2 * mi_], BSRC[2 * ni_],                              \
                        acc[(MI0) + mi_][(NI0) + ni_], 0, 0, 0);                \
                acc[(MI0) + mi_][(NI0) + ni_] =                                 \
                    __builtin_amdgcn_mfma_i32_16x16x64_i8(                      \
                        a[2 * mi_ + 1], BSRC[2 * ni_ + 1],                      \
                        acc[(MI0) + mi_][(NI0) + ni_], 0, 0, 0);                \
            }                                                                   \
        }                                                                       \
        __builtin_amdgcn_s_setprio(0);                                          \
    } while (0)

__global__ __launch_bounds__(512, 2) void gemm_i8_8ph(
    const int8_t* __restrict__ Xq,   // [M,K]
    const int8_t* __restrict__ Tq,   // [N,K]
    const float* __restrict__ scale, // [M]
    const float* __restrict__ bias,  // [N]
    float* __restrict__ out) {
    extern __shared__ __align__(16) int8_t lds[];  // 131072 B
    const int K = IN_F;
    const int NT = K / 128;   // 32 K-tiles
    const int NI = NT / 2;    // 16 iterations

    const int t = threadIdx.x;
    const int lane = t & 63;
    const int wave = t >> 6;
    const int lm = lane & 15;
    const int qh = lane >> 4;             // 0..3
    const int wm = (wave >> 2) << 7;      // 0 / 128
    const int wn = (wave & 3) << 6;       // 0/64/128/192

    // T1: bijective XCD swizzle (gridDim.x % 8 == 0)
    const int nwg = gridDim.x;
    const int id = blockIdx.x;
    const int swz = (id & 7) * (nwg >> 3) + (id >> 3);
    const int m0 = (swz >> 4) << 8;       // 32 M-tiles
    const int n0 = (swz & 15) << 8;       // 16 N-tiles

    int8_t* const A0  = lds;              // buf0 A (32 KB)
    int8_t* const B0  = lds + 32768;      // buf0 B
    int8_t* const A1b = lds + 65536;      // buf1 A
    int8_t* const B1b = lds + 98304;      // buf1 B

    // T2 swizzled fragment offsets: slot(kk) = (kk*4 + qh) ^ (lm&7)
    const int swzs = lm & 7;
    const int offA_k0 = (wm + lm) * 128 + ((qh ^ swzs) << 4);
    const int offA_k1 = (wm + lm) * 128 + (((4 + qh) ^ swzs) << 4);
    const int offB_k0 = (wn + lm) * 128 + ((qh ^ swzs) << 4);
    const int offB_k1 = (wn + lm) * 128 + (((4 + qh) ^ swzs) << 4);

    i32x4 acc[8][4];
#pragma unroll
    for (int i = 0; i < 8; ++i)
#pragma unroll
        for (int j = 0; j < 4; ++j)
#pragma unroll
            for (int r = 0; r < 4; ++r) acc[i][j][r] = 0;

    i32x4 a[8], bA[4], bB[4];

    // ---- prologue: tile0 (buf0) fully + A-lo(tile1); leave A-lo(1) in flight
    STAGE(Xq, m0, 0, A0, 0);
    STAGE(Xq, m0, 0, A0, 1);
    STAGE(Tq, n0, 0, B0, 0);
    STAGE(Tq, n0, 0, B0, 1);
    STAGE(Xq, m0, 1, A1b, 0);
    asm volatile("s_waitcnt vmcnt(2)" ::: "memory");
    GBARRIER();

#pragma unroll 1
    for (int i = 0; i < NI; ++i) {
        const int kt = 2 * i;
        // -- phase 0: read A[h0],B[v0] of buf0; stage A-hi(kt+1)->buf1
        READ_A(A0, 0);
        READ_B(B0, 0, bA);
        STAGE(Xq, m0, kt + 1, A1b, 1);
        GBARRIER();
        MFMA_Q(0, 0, bA);
        GBARRIER();
        // -- phase 1: read B[v1] of buf0; stage B-lo(kt+1)
        READ_B(B0, 2, bB);
        STAGE(Tq, n0, kt + 1, B1b, 0);
        GBARRIER();
        MFMA_Q(0, 2, bB);
        GBARRIER();
        // -- phase 2: read A[h1] of buf0; stage B-hi(kt+1)
        READ_A(A0, 4);
        STAGE(Tq, n0, kt + 1, B1b, 1);
        GBARRIER();
        MFMA_Q(4, 0, bA);
        GBARRIER();
        // -- phase 3: stage A-lo(kt+2)->buf0; K-tile boundary wait
        if (kt + 2 < NT) STAGE(Xq, m0, kt + 2, A0, 0);
        GBARRIER();
        MFMA_Q(4, 2, bB);
        if (i + 1 < NI) asm volatile("s_waitcnt vmcnt(2)" ::: "memory");
        else            asm volatile("s_waitcnt vmcnt(0)" ::: "memory");
        GBARRIER();
        // -- phase 4: read A[h0],B[v0] of buf1; stage A-hi(kt+2)
        READ_A(A1b, 0);
        READ_B(B1b, 0, bA);
        if (kt + 2 < NT) STAGE(Xq, m0, kt + 2, A0, 1);
        GBARRIER();
        MFMA_Q(0, 0, bA);
        GBARRIER();
        // -- phase 5: read B[v1] of buf1; stage B-lo(kt+2)
        READ_B(B1b, 2, bB);
        if (kt + 2 < NT) STAGE(Tq, n0, kt + 2, B0, 0);
        GBARRIER();
        MFMA_Q(0, 2, bB);
        GBARRIER();
        // -- phase 6: read A[h1] of buf1; stage B-hi(kt+2)
        READ_A(A1b, 4);
        if (kt + 2 < NT) STAGE(Tq, n0, kt + 2, B0, 1);
        GBARRIER();
        MFMA_Q(4, 0, bA);
        GBARRIER();
        // -- phase 7: stage A-lo(kt+3)->buf1; K-tile boundary wait
        if (kt + 3 < NT) STAGE(Xq, m0, kt + 3, A1b, 0);
        GBARRIER();
        MFMA_Q(4, 2, bB);
        if (i + 1 < NI) asm volatile("s_waitcnt vmcnt(2)" ::: "memory");
        GBARRIER();
    }

    // ---- epilogue: C/D layout col=lane&15, row=(lane>>4)*4+reg
    const int q4 = qh << 2;
#pragma unroll
    for (int mi = 0; mi < 8; ++mi) {
        float sc[4];
#pragma unroll
        for (int r = 0; r < 4; ++r) sc[r] = scale[m0 + wm + mi * 16 + q4 + r];
#pragma unroll
        for (int ni = 0; ni < 4; ++ni) {
            int col = n0 + wn + ni * 16 + lm;
            float b = bias[col];
#pragma unroll
            for (int r = 0; r < 4; ++r) {
                int row = m0 + wm + mi * 16 + q4 + r;
                out[(size_t)row * OUT_F + col] =
                    (float)acc[mi][ni][r] * sc[r] + b;
            }
        }
    }
}

// ---------- launch ----------

extern "C" void kernel_launch(void* const* d_in, const int* in_sizes, int n_in,
                              void* d_out, int out_size, void* d_ws, size_t ws_size,
                              hipStream_t stream) {
    const float* x = (const float*)d_in[0];
    const float* w = (const float*)d_in[1];
    const float* bias = (const float*)d_in[2];
    float* out = (float*)d_out;
    const int B = in_sizes[0] / IN_F;  // 8192

    char* ws = (char*)d_ws;
    int8_t* Tt = (int8_t*)ws;
    int8_t* T = (int8_t*)(ws + (size_t)16777216);
    int8_t* Xq = (int8_t*)(ws + (size_t)16777216);
    float* alpha = (float*)(ws + (size_t)50331648);
    float* scale = (float*)(ws + (size_t)50331648 + 16384);

    static int lds_set = 0;
    if (!lds_set) {
        hipFuncSetAttribute((const void*)gemm_i8_8ph,
                            hipFuncAttributeMaxDynamicSharedMemorySize, 131072);
        lds_set = 1;
    }

    rowstats_tern_kernel<<<IN_F, 256, 0, stream>>>(w, alpha, T);
    transpose_i8_kernel<<<dim3(OUT_F / 64, IN_F / 64), 256, 0, stream>>>(T, Tt);
    xquant_kernel<<<B, 256, 0, stream>>>(x, alpha, Xq, scale);
    const int nwg = (B / 256) * (OUT_F / 256);  // 512
    gemm_i8_8ph<<<dim3(nwg), dim3(512), 131072, stream>>>(Xq, Tt, scale, bias, out);
}